// Round 15
// baseline (291.394 us; speedup 1.0000x reference)
//
#include <hip/hip_runtime.h>
#include <math.h>

#define NFEAT 512
#define NHID  128
#define NCLASS 16
#define SCAN_BS 512
#define AGG_BLOCKS 2048   // 512 blocks per slice (slice = b&3) -> 8 blocks/CU, 32 waves/CU
#define NSTREAMS 32768    // 512 x 4 waves x 16 streams

typedef __attribute__((ext_vector_type(8))) short short8;
typedef __attribute__((ext_vector_type(4))) float f32x4;

static __device__ __forceinline__ ushort f2b(float f) {
    union { float f; uint u; } v; v.f = f;
    uint r = v.u + 0x7FFFu + ((v.u >> 16) & 1u);   // round-to-nearest-even
    return (ushort)(r >> 16);
}
static __device__ __forceinline__ float b2f_lo(uint bits) {
    union { uint u; float f; } v; v.u = bits << 16; return v.f;
}
static __device__ __forceinline__ float b2f_hi(uint bits) {
    union { uint u; float f; } v; v.u = bits & 0xffff0000u; return v.f;
}

// ---------------- prep: weight transpose/cast + degree count (deg pre-zeroed) ----------

__global__ void k_prep(const float* __restrict__ W1, const float* __restrict__ W2,
                       ushort* __restrict__ W1T, ushort* __restrict__ W2T,
                       const int* __restrict__ dst, int e,
                       int* __restrict__ deg, int* __restrict__ ticket) {
    int i = blockIdx.x * blockDim.x + threadIdx.x;
    if (i < (NFEAT + NHID) * 128) {
        if (i < NFEAT * 128) {
            int k = i >> 7, c = i & 127;
            W1T[(size_t)c * NFEAT + k] = f2b(W1[i]);
        } else {
            int j = i - NFEAT * 128;
            int k = j >> 7, c = j & 127;
            W2T[(size_t)c * NHID + k] = f2b(W2[j]);
        }
    }
    if (i < e) ticket[i] = atomicAdd(&deg[dst[i]], 1);   // 0-based edge slot
}

// chunk-local exclusive scan of (deg+1) + chunk sums + dinv (for GEMM rowscale)
__global__ void k_scan1(const int* __restrict__ deg, float* __restrict__ dinv,
                        int* __restrict__ offs, int* __restrict__ bsum, int n) {
    __shared__ int s[SCAN_BS];
    int t = threadIdx.x;
    int i = blockIdx.x * SCAN_BS + t;
    int d = (i < n) ? (deg[i] + 1) : 0;     // +1 self-loop
    if (i < n) dinv[i] = rsqrtf((float)d);
    s[t] = d;
    for (int off = 1; off < SCAN_BS; off <<= 1) {
        __syncthreads();
        int x = (t >= off) ? s[t - off] : 0;
        __syncthreads();
        s[t] += x;
    }
    __syncthreads();
    if (i < n) offs[i] = s[t] - d;          // chunk-local exclusive
    if (t == SCAN_BS - 1) bsum[blockIdx.x] = s[t];
}

// edge scatter (atomic-free via ticket) + self/meta slot + streamed fdvp + rankgs + pad.
// offs is chunk-local; each block rebuilds the <=128-chunk prefix in smem.
// colp32[slot] = src | (v+1)<<16 on last slot (self-loop) of node v, else src.
// fdvp[slot]  = rsqrt(deg+1) on last slot of node v (garbage elsewhere, never used).
__global__ void k_fill_edges(const int* __restrict__ src, const int* __restrict__ dst, int e,
                             const int* __restrict__ offs, const int* __restrict__ bsum,
                             const int* __restrict__ ticket, uint* __restrict__ colp32,
                             float* __restrict__ fdvp, int* __restrict__ rankgs,
                             int n, int S, int nbch) {
    __shared__ int incl[128];
    int tid = threadIdx.x;
    if (tid < 64) {
        int carry = 0;
        for (int base = 0; base < nbch; base += 64) {
            int j = base + tid;
            int v = (j < nbch) ? bsum[j] : 0;
            for (int off = 1; off < 64; off <<= 1) {
                int x = __shfl_up(v, off);
                if (tid >= off) v += x;
            }
            if (j < nbch) incl[j] = carry + v;   // inclusive chunk prefix
            carry += __shfl(v, 63);
        }
    }
    __syncthreads();

    auto absoff = [&](int v) -> int {
        if (v >= n) return S;
        int c = v >> 9;                           // SCAN_BS = 512
        return offs[v] + (c ? incl[c - 1] : 0);
    };

    int i = blockIdx.x * blockDim.x + tid;
    if (i < e) {
        colp32[absoff(dst[i]) + ticket[i]] = (uint)src[i];   // meta 0
    }
    if (i < n) {
        int o0 = absoff(i), o1 = absoff(i + 1);
        colp32[o1 - 1] = (uint)i | ((uint)(i + 1) << 16);    // self-loop + boundary meta
        fdvp[o1 - 1] = rsqrtf((float)(o1 - o0));             // = dinv[i]
    }
    if (i < NSTREAMS) {
        int len = (S + NSTREAMS - 1) / NSTREAMS;
        int target = i * len;
        int lo = 0, hi = n;
        while (lo < hi) {                         // first v with absoff(v) >= target
            int mid = (lo + hi) >> 1;
            if (absoff(mid) < target) lo = mid + 1; else hi = mid;
        }
        rankgs[i] = absoff(lo);
        if (i == 0) rankgs[NSTREAMS] = S;
    }
    if (i == 0) {
#pragma unroll
        for (int k = 0; k < 8; k++) colp32[S + k] = 0;   // prefetch pad
    }
}

// ---------------- bf16 MFMA GEMM, 64x128 tile -> 4-slice output ----------------
// 4 waves; wave wc owns output cols [wc*32, wc*32+32) = slice wc.
// Hs layout: [slice(4)][node(M)][32 feats] bf16, pre-scaled by rowscale[row].

template<int A_F32>
__global__ __launch_bounds__(256) void k_gemm(const void* __restrict__ Aptr,
                                              const ushort* __restrict__ WT,
                                              const float* __restrict__ rowscale,
                                              ushort* __restrict__ Hs, int M, int K) {
    __shared__ ushort As[64][40];   // pad 40: <=2-way bank conflict (free)
    __shared__ ushort Bs[128][40];

    const int tid = threadIdx.x;
    const int wc = tid >> 6, lane = tid & 63;
    const int lr = lane & 15, lk = (lane >> 4) * 8;
    const int rowbase = blockIdx.x * 64;

    f32x4 acc[4][2];
#pragma unroll
    for (int i = 0; i < 4; i++)
#pragma unroll
        for (int j = 0; j < 2; j++) acc[i][j] = (f32x4)0.f;

    const int sr = tid >> 2;        // staging row 0..63
    const int sh = (tid & 3) * 8;   // staging octet

    for (int k0 = 0; k0 < K; k0 += 32) {
        {
            int gr = rowbase + sr;
            ushort tmp[8];
            if (A_F32) {
                const float* A = (const float*)Aptr;
                if (gr < M) {
                    const float* p = A + (size_t)gr * K + k0 + sh;
#pragma unroll
                    for (int q = 0; q < 2; q++) {
                        float4 v = *(const float4*)(p + q * 4);
                        tmp[q * 4 + 0] = f2b(v.x); tmp[q * 4 + 1] = f2b(v.y);
                        tmp[q * 4 + 2] = f2b(v.z); tmp[q * 4 + 3] = f2b(v.w);
                    }
                } else {
#pragma unroll
                    for (int q = 0; q < 8; q++) tmp[q] = 0;
                }
            } else {
                const ushort* A = (const ushort*)Aptr;
                if (gr < M) {
                    *(short8*)&tmp[0] = *(const short8*)(A + (size_t)gr * K + k0 + sh);
                } else {
#pragma unroll
                    for (int q = 0; q < 8; q++) tmp[q] = 0;
                }
            }
            *(short8*)&As[sr][sh] = *(short8*)&tmp[0];
        }
        {
#pragma unroll
            for (int t = 0; t < 2; t++) {
                int c = tid + t * 256;
                int row = c >> 2, q = c & 3;
                short8 v = *(const short8*)(WT + (size_t)row * K + k0 + q * 8);
                *(short8*)&Bs[row][q * 8] = v;
            }
        }
        __syncthreads();

        short8 af[4], bfv[2];
#pragma unroll
        for (int i = 0; i < 4; i++) af[i] = *(const short8*)&As[i * 16 + lr][lk];
#pragma unroll
        for (int j = 0; j < 2; j++) bfv[j] = *(const short8*)&Bs[wc * 32 + j * 16 + lr][lk];
#pragma unroll
        for (int i = 0; i < 4; i++)
#pragma unroll
            for (int j = 0; j < 2; j++)
                acc[i][j] = __builtin_amdgcn_mfma_f32_16x16x32_bf16(af[i], bfv[j], acc[i][j], 0, 0, 0);
        __syncthreads();
    }

#pragma unroll
    for (int i = 0; i < 4; i++) {
#pragma unroll
        for (int r = 0; r < 4; r++) {
            int row = rowbase + i * 16 + (lane >> 4) * 4 + r;
            if (row < M) {
                float sc = rowscale[row];
#pragma unroll
                for (int j = 0; j < 2; j++) {
                    int f = j * 16 + lr;
                    Hs[((size_t)wc * M + row) * 32 + f] = f2b(acc[i][j][r] * sc);
                }
            }
        }
    }
}

// ---------------- stream-parallel segmented aggregation, depth-5, 32 waves/CU ----------
// 16 streams per wave (4 lanes x 16B each); stream owns exact node range
// [rankgs[r], rankgs[r+1]); flush at node boundary (meta word). dinv arrives via the
// streamed fdvp array (same linear prefetch as colp32) - no random dinv load.

__global__ __launch_bounds__(256, 8) void k_aggs(const ushort* __restrict__ hs,
                                                 const uint* __restrict__ colp32,
                                                 const float* __restrict__ fdvp,
                                                 const int* __restrict__ rankgs,
                                                 const float* __restrict__ bias,
                                                 ushort* __restrict__ outp, int n) {
    const int b = blockIdx.x;
    const int s = b & 3;                          // slice, pinned to XCDs {s, s+4}
    const int wid = threadIdx.x >> 6, lane = threadIdx.x & 63;
    const int st16 = lane >> 2, q = lane & 3;     // stream-in-wave, feat-quad (16B)
    const int stream = (((b >> 2) << 2) + wid) * 16 + st16;
    int g = rankgs[stream];
    int se = rankgs[stream + 1];
    bool alive = g < se;
    if (!alive) g = 0;

    const ushort* hsl = hs + (size_t)s * n * 32;
    const float4 bv0 = *(const float4*)(bias + s * 32 + q * 8);
    const float4 bv1 = *(const float4*)(bias + s * 32 + q * 8 + 4);

    const uint* cp = colp32 + g;
    const float* fp = fdvp + g;
    uint cw0 = cp[0], cw1 = cp[1], cw2 = cp[2], cw3 = cp[3], cw4 = cp[4];
    float fv0 = fp[0], fv1 = fp[1], fv2 = fp[2], fv3 = fp[3], fv4 = fp[4];
    uint4 pk0 = *(const uint4*)(hsl + (size_t)(cw0 & 0xffffu) * 32 + q * 8);
    uint4 pk1 = *(const uint4*)(hsl + (size_t)(cw1 & 0xffffu) * 32 + q * 8);
    uint4 pk2 = *(const uint4*)(hsl + (size_t)(cw2 & 0xffffu) * 32 + q * 8);
    uint4 pk3 = *(const uint4*)(hsl + (size_t)(cw3 & 0xffffu) * 32 + q * 8);
    float a0 = 0.f, a1 = 0.f, a2 = 0.f, a3 = 0.f;
    float a4 = 0.f, a5 = 0.f, a6 = 0.f, a7 = 0.f;

    while (__any(alive)) {
        if (alive) {
            uint cw5 = cp[5];
            float fv5 = fp[5];
            uint4 pk4 = *(const uint4*)(hsl + (size_t)(cw4 & 0xffffu) * 32 + q * 8);

            a0 += b2f_lo(pk0.x); a1 += b2f_hi(pk0.x);
            a2 += b2f_lo(pk0.y); a3 += b2f_hi(pk0.y);
            a4 += b2f_lo(pk0.z); a5 += b2f_hi(pk0.z);
            a6 += b2f_lo(pk0.w); a7 += b2f_hi(pk0.w);

            if (cw0 >> 16) {   // node boundary (per-stream, exec-masked)
                int v = (int)(cw0 >> 16) - 1;
                float r0 = fmaxf(fmaf(a0, fv0, bv0.x), 0.f);
                float r1 = fmaxf(fmaf(a1, fv0, bv0.y), 0.f);
                float r2 = fmaxf(fmaf(a2, fv0, bv0.z), 0.f);
                float r3 = fmaxf(fmaf(a3, fv0, bv0.w), 0.f);
                float r4 = fmaxf(fmaf(a4, fv0, bv1.x), 0.f);
                float r5 = fmaxf(fmaf(a5, fv0, bv1.y), 0.f);
                float r6 = fmaxf(fmaf(a6, fv0, bv1.z), 0.f);
                float r7 = fmaxf(fmaf(a7, fv0, bv1.w), 0.f);
                uint4 u;
                u.x = (uint)f2b(r0) | ((uint)f2b(r1) << 16);
                u.y = (uint)f2b(r2) | ((uint)f2b(r3) << 16);
                u.z = (uint)f2b(r4) | ((uint)f2b(r5) << 16);
                u.w = (uint)f2b(r6) | ((uint)f2b(r7) << 16);
                *(uint4*)(outp + (size_t)v * 128 + s * 32 + q * 8) = u;
                a0 = a1 = a2 = a3 = a4 = a5 = a6 = a7 = 0.f;
                if (g + 1 >= se) alive = false;
            }
            g++; cp++; fp++;
            cw0 = cw1; cw1 = cw2; cw2 = cw3; cw3 = cw4; cw4 = cw5;
            fv0 = fv1; fv1 = fv2; fv2 = fv3; fv3 = fv4; fv4 = fv5;
            pk0 = pk1; pk1 = pk2; pk2 = pk3; pk3 = pk4;
        }
    }
}

// ---------------- classifier + log_softmax (bf16 hidden input, row-major) ----------------

__global__ __launch_bounds__(256) void k_classify(const ushort* __restrict__ h,
                                                  const float* __restrict__ Wc,
                                                  const float* __restrict__ bc,
                                                  float* __restrict__ out, int n) {
    __shared__ float Ws[128 * 16];
    int tid = threadIdx.x;
#pragma unroll
    for (int t = 0; t < 8; t++) Ws[tid + 256 * t] = Wc[tid + 256 * t];
    __syncthreads();

    int wid = tid >> 6, lane = tid & 63;
    int v = blockIdx.x * 4 + wid;
    if (v >= n) return;

    int j = lane & 15, c = lane >> 4;
    const ushort* hv = h + (size_t)v * 128 + c * 32;
    float acc = 0.f;
#pragma unroll
    for (int t = 0; t < 16; t++) {
        uint pk = *(const uint*)(hv + t * 2);
        acc = fmaf(b2f_lo(pk), Ws[(c * 32 + t * 2 + 0) * 16 + j], acc);
        acc = fmaf(b2f_hi(pk), Ws[(c * 32 + t * 2 + 1) * 16 + j], acc);
    }
    acc += __shfl_xor(acc, 16);
    acc += __shfl_xor(acc, 32);
    acc += bc[j];

    float m = acc;
#pragma unroll
    for (int o = 8; o >= 1; o >>= 1) m = fmaxf(m, __shfl_xor(m, o));
    float sum = expf(acc - m);
#pragma unroll
    for (int o = 8; o >= 1; o >>= 1) sum += __shfl_xor(sum, o);
    if (lane < 16) out[(size_t)v * 16 + j] = acc - m - logf(sum);
}

// ---------------- launch ----------------

extern "C" void kernel_launch(void* const* d_in, const int* in_sizes, int n_in,
                              void* d_out, int out_size, void* d_ws, size_t ws_size,
                              hipStream_t stream) {
    const float* x  = (const float*)d_in[0];
    const int* eidx = (const int*)d_in[1];
    const float* W1 = (const float*)d_in[2];
    const float* b1 = (const float*)d_in[3];
    const float* W2 = (const float*)d_in[4];
    const float* b2 = (const float*)d_in[5];
    const float* Wc = (const float*)d_in[6];
    const float* bc = (const float*)d_in[7];
    float* out = (float*)d_out;

    const int N = in_sizes[0] / NFEAT;   // 50000 (< 65536 -> 16-bit node ids)
    const int E = in_sizes[1] / 2;       // 800000
    const int S = E + N;                 // total slots (no padding)
    const int* src = eidx;
    const int* dst = eidx + E;

    char* p = (char*)d_ws;
    auto alloc = [&](size_t bytes) { char* r = p; p += (bytes + 255) & ~(size_t)255; return r; };
    int*    deg    = (int*)   alloc((size_t)N * 4);
    float*  dinv   = (float*) alloc((size_t)N * 4);
    int*    eoffs  = (int*)   alloc((size_t)(N + 1) * 4);
    int*    ticket = (int*)   alloc((size_t)E * 4);
    uint*   colp32 = (uint*)  alloc(((size_t)S + 16) * 4);
    float*  fdvp   = (float*) alloc(((size_t)S + 16) * 4);
    int*    rankgs = (int*)   alloc((size_t)(NSTREAMS + 1) * 4);
    int*    bsum   = (int*)   alloc((size_t)256 * 4);
    ushort* W1T    = (ushort*)alloc((size_t)128 * NFEAT * 2);
    ushort* W2T    = (ushort*)alloc((size_t)128 * NHID * 2);
    ushort* hs     = (ushort*)alloc((size_t)N * NHID * 2);   // 4 slices x N x 32
    ushort* g1     = (ushort*)alloc((size_t)N * NHID * 2);   // agg1 out, row-major bf16
    ushort* g2     = (ushort*)alloc((size_t)N * NHID * 2);   // agg2 out, row-major bf16

    const int nb = (N + SCAN_BS - 1) / SCAN_BS;   // 98 <= 128

    hipMemsetAsync(deg, 0, (size_t)N * 4, stream);
    k_prep<<<(E + 255) / 256, 256, 0, stream>>>(W1, W2, W1T, W2T, dst, E, deg, ticket);
    k_scan1<<<nb, SCAN_BS, 0, stream>>>(deg, dinv, eoffs, bsum, N);
    k_fill_edges<<<(E + 255) / 256, 256, 0, stream>>>(src, dst, E, eoffs, bsum, ticket,
                                                      colp32, fdvp, rankgs, N, S, nb);

    const int gblocks = (N + 63) / 64;
    // layer 1
    k_gemm<1><<<gblocks, 256, 0, stream>>>(x, W1T, dinv, hs, N, NFEAT);
    k_aggs<<<AGG_BLOCKS, 256, 0, stream>>>(hs, colp32, fdvp, rankgs, b1, g1, N);
    // layer 2
    k_gemm<0><<<gblocks, 256, 0, stream>>>(g1, W2T, dinv, hs, N, NHID);
    k_aggs<<<AGG_BLOCKS, 256, 0, stream>>>(hs, colp32, fdvp, rankgs, b2, g2, N);
    // classifier
    k_classify<<<(N + 3) / 4, 256, 0, stream>>>(g2, Wc, bc, out, N);
}

// Round 16
// 283.178 us; speedup vs baseline: 1.0290x; 1.0290x over previous
//
#include <hip/hip_runtime.h>
#include <math.h>

#define NFEAT 512
#define NHID  128
#define NCLASS 16
#define SCAN_BS 512
#define AGG_BLOCKS 2048   // slice = b&7 == XCD; 256 blocks/XCD, 8 blocks/CU, 32 waves/CU
#define NSTREAMS 16384    // (2048/8) x 4 waves x 16 streams

typedef __attribute__((ext_vector_type(8))) short short8;
typedef __attribute__((ext_vector_type(4))) float f32x4;

static __device__ __forceinline__ ushort f2b(float f) {
    union { float f; uint u; } v; v.f = f;
    uint r = v.u + 0x7FFFu + ((v.u >> 16) & 1u);   // round-to-nearest-even
    return (ushort)(r >> 16);
}
static __device__ __forceinline__ float b2f_lo(uint bits) {
    union { uint u; float f; } v; v.u = bits << 16; return v.f;
}
static __device__ __forceinline__ float b2f_hi(uint bits) {
    union { uint u; float f; } v; v.u = bits & 0xffff0000u; return v.f;
}

// ---------------- prep: weight transpose/cast + degree count (deg pre-zeroed) ----------

__global__ void k_prep(const float* __restrict__ W1, const float* __restrict__ W2,
                       ushort* __restrict__ W1T, ushort* __restrict__ W2T,
                       const int* __restrict__ dst, int e,
                       int* __restrict__ deg, int* __restrict__ ticket) {
    int i = blockIdx.x * blockDim.x + threadIdx.x;
    if (i < (NFEAT + NHID) * 128) {
        if (i < NFEAT * 128) {
            int k = i >> 7, c = i & 127;
            W1T[(size_t)c * NFEAT + k] = f2b(W1[i]);
        } else {
            int j = i - NFEAT * 128;
            int k = j >> 7, c = j & 127;
            W2T[(size_t)c * NHID + k] = f2b(W2[j]);
        }
    }
    if (i < e) ticket[i] = atomicAdd(&deg[dst[i]], 1);   // 0-based edge slot
}

// chunk-local exclusive scan of (deg+1) + chunk sums + dinv
__global__ void k_scan1(const int* __restrict__ deg, float* __restrict__ dinv,
                        int* __restrict__ offs, int* __restrict__ bsum, int n) {
    __shared__ int s[SCAN_BS];
    int t = threadIdx.x;
    int i = blockIdx.x * SCAN_BS + t;
    int d = (i < n) ? (deg[i] + 1) : 0;     // +1 self-loop
    if (i < n) dinv[i] = rsqrtf((float)d);
    s[t] = d;
    for (int off = 1; off < SCAN_BS; off <<= 1) {
        __syncthreads();
        int x = (t >= off) ? s[t - off] : 0;
        __syncthreads();
        s[t] += x;
    }
    __syncthreads();
    if (i < n) offs[i] = s[t] - d;          // chunk-local exclusive
    if (t == SCAN_BS - 1) bsum[blockIdx.x] = s[t];
}

// edge scatter (atomic-free via ticket) + self/meta slot + rankgs + pad.
// offs is chunk-local; each block rebuilds the <=128-chunk prefix in smem.
// colp32[slot] = src | (v+1)<<16 on last slot (self-loop) of node v, else src.
__global__ void k_fill_edges(const int* __restrict__ src, const int* __restrict__ dst, int e,
                             const int* __restrict__ offs, const int* __restrict__ bsum,
                             const int* __restrict__ ticket, uint* __restrict__ colp32,
                             int* __restrict__ rankgs, int n, int S, int nbch) {
    __shared__ int incl[128];
    int tid = threadIdx.x;
    if (tid < 64) {
        int carry = 0;
        for (int base = 0; base < nbch; base += 64) {
            int j = base + tid;
            int v = (j < nbch) ? bsum[j] : 0;
            for (int off = 1; off < 64; off <<= 1) {
                int x = __shfl_up(v, off);
                if (tid >= off) v += x;
            }
            if (j < nbch) incl[j] = carry + v;   // inclusive chunk prefix
            carry += __shfl(v, 63);
        }
    }
    __syncthreads();

    auto absoff = [&](int v) -> int {
        if (v >= n) return S;
        int c = v >> 9;                           // SCAN_BS = 512
        return offs[v] + (c ? incl[c - 1] : 0);
    };

    int i = blockIdx.x * blockDim.x + tid;
    if (i < e) {
        colp32[absoff(dst[i]) + ticket[i]] = (uint)src[i];   // meta 0
    }
    if (i < n) {
        colp32[absoff(i + 1) - 1] = (uint)i | ((uint)(i + 1) << 16);  // self-loop + boundary
    }
    if (i < NSTREAMS) {
        int len = (S + NSTREAMS - 1) / NSTREAMS;
        int target = i * len;
        int lo = 0, hi = n;
        while (lo < hi) {                         // first v with absoff(v) >= target
            int mid = (lo + hi) >> 1;
            if (absoff(mid) < target) lo = mid + 1; else hi = mid;
        }
        rankgs[i] = absoff(lo);
        if (i == 0) rankgs[NSTREAMS] = S;
    }
    if (i == 0) {
#pragma unroll
        for (int k = 0; k < 8; k++) colp32[S + k] = 0;   // prefetch pad
    }
}

// ---------------- bf16 MFMA GEMM, 64x128 tile -> 8-slice output ----------------
// 4 waves; wave wc owns output cols [wc*32, wc*32+32) = slices 2wc, 2wc+1.
// Hs layout: [slice(8)][node(M)][16 feats] bf16, pre-scaled by rowscale[row].

template<int A_F32>
__global__ __launch_bounds__(256) void k_gemm(const void* __restrict__ Aptr,
                                              const ushort* __restrict__ WT,
                                              const float* __restrict__ rowscale,
                                              ushort* __restrict__ Hs, int M, int K) {
    __shared__ ushort As[64][40];   // pad 40: <=2-way bank conflict (free)
    __shared__ ushort Bs[128][40];

    const int tid = threadIdx.x;
    const int wc = tid >> 6, lane = tid & 63;
    const int lr = lane & 15, lk = (lane >> 4) * 8;
    const int rowbase = blockIdx.x * 64;

    f32x4 acc[4][2];
#pragma unroll
    for (int i = 0; i < 4; i++)
#pragma unroll
        for (int j = 0; j < 2; j++) acc[i][j] = (f32x4)0.f;

    const int sr = tid >> 2;        // staging row 0..63
    const int sh = (tid & 3) * 8;   // staging octet

    for (int k0 = 0; k0 < K; k0 += 32) {
        {
            int gr = rowbase + sr;
            ushort tmp[8];
            if (A_F32) {
                const float* A = (const float*)Aptr;
                if (gr < M) {
                    const float* p = A + (size_t)gr * K + k0 + sh;
#pragma unroll
                    for (int q = 0; q < 2; q++) {
                        float4 v = *(const float4*)(p + q * 4);
                        tmp[q * 4 + 0] = f2b(v.x); tmp[q * 4 + 1] = f2b(v.y);
                        tmp[q * 4 + 2] = f2b(v.z); tmp[q * 4 + 3] = f2b(v.w);
                    }
                } else {
#pragma unroll
                    for (int q = 0; q < 8; q++) tmp[q] = 0;
                }
            } else {
                const ushort* A = (const ushort*)Aptr;
                if (gr < M) {
                    *(short8*)&tmp[0] = *(const short8*)(A + (size_t)gr * K + k0 + sh);
                } else {
#pragma unroll
                    for (int q = 0; q < 8; q++) tmp[q] = 0;
                }
            }
            *(short8*)&As[sr][sh] = *(short8*)&tmp[0];
        }
        {
#pragma unroll
            for (int t = 0; t < 2; t++) {
                int c = tid + t * 256;
                int row = c >> 2, q = c & 3;
                short8 v = *(const short8*)(WT + (size_t)row * K + k0 + q * 8);
                *(short8*)&Bs[row][q * 8] = v;
            }
        }
        __syncthreads();

        short8 af[4], bfv[2];
#pragma unroll
        for (int i = 0; i < 4; i++) af[i] = *(const short8*)&As[i * 16 + lr][lk];
#pragma unroll
        for (int j = 0; j < 2; j++) bfv[j] = *(const short8*)&Bs[wc * 32 + j * 16 + lr][lk];
#pragma unroll
        for (int i = 0; i < 4; i++)
#pragma unroll
            for (int j = 0; j < 2; j++)
                acc[i][j] = __builtin_amdgcn_mfma_f32_16x16x32_bf16(af[i], bfv[j], acc[i][j], 0, 0, 0);
        __syncthreads();
    }

#pragma unroll
    for (int i = 0; i < 4; i++) {
#pragma unroll
        for (int r = 0; r < 4; r++) {
            int row = rowbase + i * 16 + (lane >> 4) * 4 + r;
            if (row < M) {
                float sc = rowscale[row];
#pragma unroll
                for (int j = 0; j < 2; j++) {
                    int slice = wc * 2 + j;
                    Hs[((size_t)slice * M + row) * 16 + lr] = f2b(acc[i][j][r] * sc);
                }
            }
        }
    }
}

// ---------------- stream-parallel segmented aggregation, 8 slices, 32 waves/CU ----------
// 16 streams per wave (4 lanes x 8B each = 32B/edge-slice); stream owns exact node range
// [rankgs[r], rankgs[r+1]); flush at node boundary (meta word). Slice 1.6MB + metadata
// ~2MB fits the 4MB XCD L2 (no fdvp stream - dinv is pipelined random load, 200KB).

__global__ __launch_bounds__(256, 8) void k_aggs(const ushort* __restrict__ hs,
                                                 const uint* __restrict__ colp32,
                                                 const int* __restrict__ rankgs,
                                                 const float* __restrict__ dinv,
                                                 const float* __restrict__ bias,
                                                 ushort* __restrict__ outp, int n) {
    const int b = blockIdx.x;
    const int s = b & 7;                          // slice == XCD (b%8)
    const int wid = threadIdx.x >> 6, lane = threadIdx.x & 63;
    const int st16 = lane >> 2, q = lane & 3;     // stream-in-wave, feat-quad (8B)
    const int stream = (((b >> 3) << 2) + wid) * 16 + st16;
    int g = rankgs[stream];
    int se = rankgs[stream + 1];
    bool alive = g < se;
    if (!alive) g = 0;

    const ushort* hsl = hs + (size_t)s * n * 16;
    const float4 bv = *(const float4*)(bias + s * 16 + q * 4);

    const uint* cp = colp32 + g;
    uint cw0 = cp[0], cw1 = cp[1], cw2 = cp[2], cw3 = cp[3], cw4 = cp[4];
    uint2 pk0 = *(const uint2*)(hsl + (size_t)(cw0 & 0xffffu) * 16 + q * 4);
    uint2 pk1 = *(const uint2*)(hsl + (size_t)(cw1 & 0xffffu) * 16 + q * 4);
    uint2 pk2 = *(const uint2*)(hsl + (size_t)(cw2 & 0xffffu) * 16 + q * 4);
    uint2 pk3 = *(const uint2*)(hsl + (size_t)(cw3 & 0xffffu) * 16 + q * 4);
    float fdv0 = (cw0 >> 16) ? dinv[(cw0 >> 16) - 1] : 0.f;
    float fdv1 = (cw1 >> 16) ? dinv[(cw1 >> 16) - 1] : 0.f;
    float fdv2 = (cw2 >> 16) ? dinv[(cw2 >> 16) - 1] : 0.f;
    float fdv3 = (cw3 >> 16) ? dinv[(cw3 >> 16) - 1] : 0.f;
    float a0 = 0.f, a1 = 0.f, a2 = 0.f, a3 = 0.f;

    while (__any(alive)) {
        if (alive) {
            uint cw5 = cp[5];
            uint2 pk4 = *(const uint2*)(hsl + (size_t)(cw4 & 0xffffu) * 16 + q * 4);
            float fdv4 = (cw4 >> 16) ? dinv[(cw4 >> 16) - 1] : 0.f;

            a0 += b2f_lo(pk0.x); a1 += b2f_hi(pk0.x);
            a2 += b2f_lo(pk0.y); a3 += b2f_hi(pk0.y);

            if (cw0 >> 16) {   // node boundary (per-stream, exec-masked)
                int v = (int)(cw0 >> 16) - 1;
                float r0 = fmaxf(fmaf(a0, fdv0, bv.x), 0.f);
                float r1 = fmaxf(fmaf(a1, fdv0, bv.y), 0.f);
                float r2 = fmaxf(fmaf(a2, fdv0, bv.z), 0.f);
                float r3 = fmaxf(fmaf(a3, fdv0, bv.w), 0.f);
                uint2 u;
                u.x = (uint)f2b(r0) | ((uint)f2b(r1) << 16);
                u.y = (uint)f2b(r2) | ((uint)f2b(r3) << 16);
                *(uint2*)(outp + (size_t)v * 128 + s * 16 + q * 4) = u;
                a0 = a1 = a2 = a3 = 0.f;
                if (g + 1 >= se) alive = false;
            }
            g++; cp++;
            cw0 = cw1; cw1 = cw2; cw2 = cw3; cw3 = cw4; cw4 = cw5;
            pk0 = pk1; pk1 = pk2; pk2 = pk3; pk3 = pk4;
            fdv0 = fdv1; fdv1 = fdv2; fdv2 = fdv3; fdv3 = fdv4;
        }
    }
}

// ---------------- classifier + log_softmax (bf16 hidden input, row-major) ----------------

__global__ __launch_bounds__(256) void k_classify(const ushort* __restrict__ h,
                                                  const float* __restrict__ Wc,
                                                  const float* __restrict__ bc,
                                                  float* __restrict__ out, int n) {
    __shared__ float Ws[128 * 16];
    int tid = threadIdx.x;
#pragma unroll
    for (int t = 0; t < 8; t++) Ws[tid + 256 * t] = Wc[tid + 256 * t];
    __syncthreads();

    int wid = tid >> 6, lane = tid & 63;
    int v = blockIdx.x * 4 + wid;
    if (v >= n) return;

    int j = lane & 15, c = lane >> 4;
    const ushort* hv = h + (size_t)v * 128 + c * 32;
    float acc = 0.f;
#pragma unroll
    for (int t = 0; t < 16; t++) {
        uint pk = *(const uint*)(hv + t * 2);
        acc = fmaf(b2f_lo(pk), Ws[(c * 32 + t * 2 + 0) * 16 + j], acc);
        acc = fmaf(b2f_hi(pk), Ws[(c * 32 + t * 2 + 1) * 16 + j], acc);
    }
    acc += __shfl_xor(acc, 16);
    acc += __shfl_xor(acc, 32);
    acc += bc[j];

    float m = acc;
#pragma unroll
    for (int o = 8; o >= 1; o >>= 1) m = fmaxf(m, __shfl_xor(m, o));
    float sum = expf(acc - m);
#pragma unroll
    for (int o = 8; o >= 1; o >>= 1) sum += __shfl_xor(sum, o);
    if (lane < 16) out[(size_t)v * 16 + j] = acc - m - logf(sum);
}

// ---------------- launch ----------------

extern "C" void kernel_launch(void* const* d_in, const int* in_sizes, int n_in,
                              void* d_out, int out_size, void* d_ws, size_t ws_size,
                              hipStream_t stream) {
    const float* x  = (const float*)d_in[0];
    const int* eidx = (const int*)d_in[1];
    const float* W1 = (const float*)d_in[2];
    const float* b1 = (const float*)d_in[3];
    const float* W2 = (const float*)d_in[4];
    const float* b2 = (const float*)d_in[5];
    const float* Wc = (const float*)d_in[6];
    const float* bc = (const float*)d_in[7];
    float* out = (float*)d_out;

    const int N = in_sizes[0] / NFEAT;   // 50000 (< 65536 -> 16-bit node ids)
    const int E = in_sizes[1] / 2;       // 800000
    const int S = E + N;                 // total slots (no padding)
    const int* src = eidx;
    const int* dst = eidx + E;

    char* p = (char*)d_ws;
    auto alloc = [&](size_t bytes) { char* r = p; p += (bytes + 255) & ~(size_t)255; return r; };
    int*    deg    = (int*)   alloc((size_t)N * 4);
    float*  dinv   = (float*) alloc((size_t)N * 4);
    int*    eoffs  = (int*)   alloc((size_t)(N + 1) * 4);
    int*    ticket = (int*)   alloc((size_t)E * 4);
    uint*   colp32 = (uint*)  alloc(((size_t)S + 16) * 4);
    int*    rankgs = (int*)   alloc((size_t)(NSTREAMS + 1) * 4);
    int*    bsum   = (int*)   alloc((size_t)256 * 4);
    ushort* W1T    = (ushort*)alloc((size_t)128 * NFEAT * 2);
    ushort* W2T    = (ushort*)alloc((size_t)128 * NHID * 2);
    ushort* hs     = (ushort*)alloc((size_t)N * NHID * 2);   // 8 slices x N x 16
    ushort* g1     = (ushort*)alloc((size_t)N * NHID * 2);   // agg1 out, row-major bf16
    ushort* g2     = (ushort*)alloc((size_t)N * NHID * 2);   // agg2 out, row-major bf16

    const int nb = (N + SCAN_BS - 1) / SCAN_BS;   // 98 <= 128

    hipMemsetAsync(deg, 0, (size_t)N * 4, stream);
    k_prep<<<(E + 255) / 256, 256, 0, stream>>>(W1, W2, W1T, W2T, dst, E, deg, ticket);
    k_scan1<<<nb, SCAN_BS, 0, stream>>>(deg, dinv, eoffs, bsum, N);
    k_fill_edges<<<(E + 255) / 256, 256, 0, stream>>>(src, dst, E, eoffs, bsum, ticket,
                                                      colp32, rankgs, N, S, nb);

    const int gblocks = (N + 63) / 64;
    // layer 1
    k_gemm<1><<<gblocks, 256, 0, stream>>>(x, W1T, dinv, hs, N, NFEAT);
    k_aggs<<<AGG_BLOCKS, 256, 0, stream>>>(hs, colp32, rankgs, dinv, b1, g1, N);
    // layer 2
    k_gemm<0><<<gblocks, 256, 0, stream>>>(g1, W2T, dinv, hs, N, NHID);
    k_aggs<<<AGG_BLOCKS, 256, 0, stream>>>(hs, colp32, rankgs, dinv, b2, g2, N);
    // classifier
    k_classify<<<(N + 3) / 4, 256, 0, stream>>>(g2, Wc, bc, out, N);
}

// Round 17
// 227.597 us; speedup vs baseline: 1.2803x; 1.2442x over previous
//
#include <hip/hip_runtime.h>
#include <math.h>

#define NFEAT 512
#define NHID  128
#define NCLASS 16
#define SCAN_BS 512
#define AGG_BLOCKS 1024   // 256 blocks per slice (slice = b&3)
#define NSTREAMS 16384    // 1024 blocks x 4 waves x 16 streams

typedef __attribute__((ext_vector_type(8))) short short8;
typedef __attribute__((ext_vector_type(4))) float f32x4;

static __device__ __forceinline__ ushort f2b(float f) {
    union { float f; uint u; } v; v.f = f;
    uint r = v.u + 0x7FFFu + ((v.u >> 16) & 1u);   // round-to-nearest-even
    return (ushort)(r >> 16);
}
static __device__ __forceinline__ float b2f_lo(uint bits) {
    union { uint u; float f; } v; v.u = bits << 16; return v.f;
}
static __device__ __forceinline__ float b2f_hi(uint bits) {
    union { uint u; float f; } v; v.u = bits & 0xffff0000u; return v.f;
}

// ---------------- init: deg=1 (self-loop) + weight transpose/cast ----------

__global__ void k_init_tcast(const float* __restrict__ W1, const float* __restrict__ W2,
                             ushort* __restrict__ W1T, ushort* __restrict__ W2T,
                             int* __restrict__ deg, int n) {
    int idx = blockIdx.x * 256 + threadIdx.x;
    if (idx < n) deg[idx] = 1;
    if (idx < NFEAT * 128) {
        int k = idx >> 7, c = idx & 127;
        W1T[(size_t)c * NFEAT + k] = f2b(W1[idx]);
    } else {
        int j = idx - NFEAT * 128;
        if (j < NHID * 128) {
            int k = j >> 7, c = j & 127;
            W2T[(size_t)c * NHID + k] = f2b(W2[j]);
        }
    }
}

// count + ticket: atomic return value = slot index within node (1-based; deg starts at 1)
__global__ void k_count(const int* __restrict__ dst, int e, int* __restrict__ deg,
                        int* __restrict__ ticket) {
    int i = blockIdx.x * blockDim.x + threadIdx.x;
    if (i < e) ticket[i] = atomicAdd(&deg[dst[i]], 1);
}

// scan deg (edge offsets, no padding) fused with dinv init
__global__ void k_scan1(const int* __restrict__ deg, float* __restrict__ dinv,
                        int* __restrict__ offs, int* __restrict__ bsum, int n) {
    __shared__ int s[SCAN_BS];
    int t = threadIdx.x;
    int i = blockIdx.x * SCAN_BS + t;
    int d = (i < n) ? deg[i] : 0;
    if (i < n) dinv[i] = rsqrtf((float)d);
    s[t] = d;
    for (int off = 1; off < SCAN_BS; off <<= 1) {
        __syncthreads();
        int x = (t >= off) ? s[t - off] : 0;
        __syncthreads();
        s[t] += x;
    }
    __syncthreads();
    if (i < n) offs[i] = s[t] - d;
    if (t == SCAN_BS - 1) bsum[blockIdx.x] = s[t];
}

// scan3 with scan2 folded in: every block re-scans the (<=128) block sums itself
__global__ void k_scan3(int* __restrict__ offs, const int* __restrict__ bsum, int nb, int n) {
    __shared__ int pref[128];
    int t = threadIdx.x;
    if (t < 64) {
        int carry = 0;
        for (int base = 0; base < nb; base += 64) {
            int j = base + t;
            int v = (j < nb) ? bsum[j] : 0;
            for (int off = 1; off < 64; off <<= 1) {
                int x = __shfl_up(v, off);
                if (t >= off) v += x;
            }
            if (j < nb) pref[j] = carry + v;   // inclusive prefix
            carry += __shfl(v, 63);
        }
    }
    __syncthreads();
    int i = blockIdx.x * SCAN_BS + t;
    int add = blockIdx.x ? pref[blockIdx.x - 1] : 0;
    if (i < n) offs[i] += add;
    if (blockIdx.x == 0 && t == 0) offs[n] = pref[nb - 1];   // = S
}

// atomic-free edge scatter + self/meta slot + pad words + stream-start table
// colp32[slot] = src(16b) | meta(16b); meta = dst+1 on the LAST slot (self-loop) of each node.
__global__ void k_fill_edges(const int* __restrict__ src, const int* __restrict__ dst, int e,
                             const int* __restrict__ eoffs, const int* __restrict__ ticket,
                             uint* __restrict__ colp32, int* __restrict__ rankgs,
                             int n, int S) {
    int i = blockIdx.x * blockDim.x + threadIdx.x;
    if (i < e) {
        colp32[eoffs[dst[i]] + ticket[i] - 1] = (uint)src[i];   // meta 0
    }
    if (i < n) {
        colp32[eoffs[i + 1] - 1] = (uint)i | ((uint)(i + 1) << 16);  // self-loop + boundary meta
    }
    if (i < NSTREAMS) {
        int len = (S + NSTREAMS - 1) / NSTREAMS;
        int target = i * len;
        int lo = 0, hi = n;                       // eoffs[n] = S
        while (lo < hi) {                         // lower_bound: first eoffs[v] >= target
            int mid = (lo + hi) >> 1;
            if (eoffs[mid] < target) lo = mid + 1; else hi = mid;
        }
        rankgs[i] = eoffs[lo];
        if (i == 0) rankgs[NSTREAMS] = S;
    }
    if (i == 0) {
#pragma unroll
        for (int k = 0; k < 8; k++) colp32[S + k] = 0;   // prefetch pad (src 0, no meta)
    }
}

// ---------------- bf16 MFMA GEMM, 64x128 tile -> 4-slice output ----------------
// 4 waves; wave wc owns output cols [wc*32, wc*32+32) = slice wc.
// Hs layout: [slice(4)][node(M)][32 feats] bf16, pre-scaled by rowscale[row].

template<int A_F32>
__global__ __launch_bounds__(256) void k_gemm(const void* __restrict__ Aptr,
                                              const ushort* __restrict__ WT,
                                              const float* __restrict__ rowscale,
                                              ushort* __restrict__ Hs, int M, int K) {
    __shared__ ushort As[64][40];   // pad 40: <=2-way bank conflict (free)
    __shared__ ushort Bs[128][40];

    const int tid = threadIdx.x;
    const int wc = tid >> 6, lane = tid & 63;
    const int lr = lane & 15, lk = (lane >> 4) * 8;
    const int rowbase = blockIdx.x * 64;

    f32x4 acc[4][2];
#pragma unroll
    for (int i = 0; i < 4; i++)
#pragma unroll
        for (int j = 0; j < 2; j++) acc[i][j] = (f32x4)0.f;

    const int sr = tid >> 2;        // staging row 0..63
    const int sh = (tid & 3) * 8;   // staging octet

    for (int k0 = 0; k0 < K; k0 += 32) {
        {
            int gr = rowbase + sr;
            ushort tmp[8];
            if (A_F32) {
                const float* A = (const float*)Aptr;
                if (gr < M) {
                    const float* p = A + (size_t)gr * K + k0 + sh;
#pragma unroll
                    for (int q = 0; q < 2; q++) {
                        float4 v = *(const float4*)(p + q * 4);
                        tmp[q * 4 + 0] = f2b(v.x); tmp[q * 4 + 1] = f2b(v.y);
                        tmp[q * 4 + 2] = f2b(v.z); tmp[q * 4 + 3] = f2b(v.w);
                    }
                } else {
#pragma unroll
                    for (int q = 0; q < 8; q++) tmp[q] = 0;
                }
            } else {
                const ushort* A = (const ushort*)Aptr;
                if (gr < M) {
                    *(short8*)&tmp[0] = *(const short8*)(A + (size_t)gr * K + k0 + sh);
                } else {
#pragma unroll
                    for (int q = 0; q < 8; q++) tmp[q] = 0;
                }
            }
            *(short8*)&As[sr][sh] = *(short8*)&tmp[0];
        }
        {
#pragma unroll
            for (int t = 0; t < 2; t++) {
                int c = tid + t * 256;
                int row = c >> 2, q = c & 3;
                short8 v = *(const short8*)(WT + (size_t)row * K + k0 + q * 8);
                *(short8*)&Bs[row][q * 8] = v;
            }
        }
        __syncthreads();

        short8 af[4], bfv[2];
#pragma unroll
        for (int i = 0; i < 4; i++) af[i] = *(const short8*)&As[i * 16 + lr][lk];
#pragma unroll
        for (int j = 0; j < 2; j++) bfv[j] = *(const short8*)&Bs[wc * 32 + j * 16 + lr][lk];
#pragma unroll
        for (int i = 0; i < 4; i++)
#pragma unroll
            for (int j = 0; j < 2; j++)
                acc[i][j] = __builtin_amdgcn_mfma_f32_16x16x32_bf16(af[i], bfv[j], acc[i][j], 0, 0, 0);
        __syncthreads();
    }

#pragma unroll
    for (int i = 0; i < 4; i++) {
#pragma unroll
        for (int r = 0; r < 4; r++) {
            int row = rowbase + i * 16 + (lane >> 4) * 4 + r;
            if (row < M) {
                float sc = rowscale[row];
#pragma unroll
                for (int j = 0; j < 2; j++) {
                    int f = j * 16 + lr;
                    Hs[((size_t)wc * M + row) * 32 + f] = f2b(acc[i][j][r] * sc);
                }
            }
        }
    }
}

// ---------------- stream-parallel segmented aggregation, depth-4 pipeline ----------------
// 16 streams per wave (4 lanes x 16B each); stream owns exact node range
// [rankgs[r], rankgs[r+1]); flush at node boundary (meta word), no cross-lane reduce.

__global__ __launch_bounds__(256) void k_aggs(const ushort* __restrict__ hs,
                                              const uint* __restrict__ colp32,
                                              const int* __restrict__ rankgs,
                                              const float* __restrict__ dinv,
                                              const float* __restrict__ bias,
                                              ushort* __restrict__ outp, int n) {
    const int b = blockIdx.x;
    const int s = b & 3;                          // slice, pinned to XCDs {s, s+4}
    const int wid = threadIdx.x >> 6, lane = threadIdx.x & 63;
    const int st16 = lane >> 2, q = lane & 3;     // stream-in-wave, feat-quad (16B)
    const int stream = (((b >> 2) << 2) + wid) * 16 + st16;
    int g = rankgs[stream];
    int se = rankgs[stream + 1];
    bool alive = g < se;
    if (!alive) g = 0;

    const ushort* hsl = hs + (size_t)s * n * 32;
    const float4 bv0 = *(const float4*)(bias + s * 32 + q * 8);
    const float4 bv1 = *(const float4*)(bias + s * 32 + q * 8 + 4);

    const uint* cp = colp32 + g;
    uint cw0 = cp[0], cw1 = cp[1], cw2 = cp[2], cw3 = cp[3];
    uint4 pk0 = *(const uint4*)(hsl + (size_t)(cw0 & 0xffffu) * 32 + q * 8);
    uint4 pk1 = *(const uint4*)(hsl + (size_t)(cw1 & 0xffffu) * 32 + q * 8);
    uint4 pk2 = *(const uint4*)(hsl + (size_t)(cw2 & 0xffffu) * 32 + q * 8);
    float fdv0 = (cw0 >> 16) ? dinv[(cw0 >> 16) - 1] : 0.f;
    float fdv1 = (cw1 >> 16) ? dinv[(cw1 >> 16) - 1] : 0.f;
    float fdv2 = (cw2 >> 16) ? dinv[(cw2 >> 16) - 1] : 0.f;
    float a0 = 0.f, a1 = 0.f, a2 = 0.f, a3 = 0.f;
    float a4 = 0.f, a5 = 0.f, a6 = 0.f, a7 = 0.f;

    while (__any(alive)) {
        if (alive) {
            uint cw4 = cp[4];
            uint4 pk3 = *(const uint4*)(hsl + (size_t)(cw3 & 0xffffu) * 32 + q * 8);
            float fdv3 = (cw3 >> 16) ? dinv[(cw3 >> 16) - 1] : 0.f;

            a0 += b2f_lo(pk0.x); a1 += b2f_hi(pk0.x);
            a2 += b2f_lo(pk0.y); a3 += b2f_hi(pk0.y);
            a4 += b2f_lo(pk0.z); a5 += b2f_hi(pk0.z);
            a6 += b2f_lo(pk0.w); a7 += b2f_hi(pk0.w);

            if (cw0 >> 16) {
                int v = (int)(cw0 >> 16) - 1;
                float r0 = fmaxf(fmaf(a0, fdv0, bv0.x), 0.f);
                float r1 = fmaxf(fmaf(a1, fdv0, bv0.y), 0.f);
                float r2 = fmaxf(fmaf(a2, fdv0, bv0.z), 0.f);
                float r3 = fmaxf(fmaf(a3, fdv0, bv0.w), 0.f);
                float r4 = fmaxf(fmaf(a4, fdv0, bv1.x), 0.f);
                float r5 = fmaxf(fmaf(a5, fdv0, bv1.y), 0.f);
                float r6 = fmaxf(fmaf(a6, fdv0, bv1.z), 0.f);
                float r7 = fmaxf(fmaf(a7, fdv0, bv1.w), 0.f);
                uint4 u;
                u.x = (uint)f2b(r0) | ((uint)f2b(r1) << 16);
                u.y = (uint)f2b(r2) | ((uint)f2b(r3) << 16);
                u.z = (uint)f2b(r4) | ((uint)f2b(r5) << 16);
                u.w = (uint)f2b(r6) | ((uint)f2b(r7) << 16);
                *(uint4*)(outp + (size_t)v * 128 + s * 32 + q * 8) = u;
                a0 = a1 = a2 = a3 = a4 = a5 = a6 = a7 = 0.f;
                if (g + 1 >= se) alive = false;
            }
            g++; cp++;
            cw0 = cw1; cw1 = cw2; cw2 = cw3; cw3 = cw4;
            pk0 = pk1; pk1 = pk2; pk2 = pk3;
            fdv0 = fdv1; fdv1 = fdv2; fdv2 = fdv3;
        }
    }
}

// ---------------- classifier + log_softmax (bf16 hidden input, row-major) ----------------

__global__ __launch_bounds__(256) void k_classify(const ushort* __restrict__ h,
                                                  const float* __restrict__ Wc,
                                                  const float* __restrict__ bc,
                                                  float* __restrict__ out, int n) {
    __shared__ float Ws[128 * 16];
    int tid = threadIdx.x;
#pragma unroll
    for (int t = 0; t < 8; t++) Ws[tid + 256 * t] = Wc[tid + 256 * t];
    __syncthreads();

    int wid = tid >> 6, lane = tid & 63;
    int v = blockIdx.x * 4 + wid;
    if (v >= n) return;

    int j = lane & 15, c = lane >> 4;
    const ushort* hv = h + (size_t)v * 128 + c * 32;
    float acc = 0.f;
#pragma unroll
    for (int t = 0; t < 16; t++) {
        uint pk = *(const uint*)(hv + t * 2);
        acc = fmaf(b2f_lo(pk), Ws[(c * 32 + t * 2 + 0) * 16 + j], acc);
        acc = fmaf(b2f_hi(pk), Ws[(c * 32 + t * 2 + 1) * 16 + j], acc);
    }
    acc += __shfl_xor(acc, 16);
    acc += __shfl_xor(acc, 32);
    acc += bc[j];

    float m = acc;
#pragma unroll
    for (int o = 8; o >= 1; o >>= 1) m = fmaxf(m, __shfl_xor(m, o));
    float sum = expf(acc - m);
#pragma unroll
    for (int o = 8; o >= 1; o >>= 1) sum += __shfl_xor(sum, o);
    if (lane < 16) out[(size_t)v * 16 + j] = acc - m - logf(sum);
}

// ---------------- launch ----------------

extern "C" void kernel_launch(void* const* d_in, const int* in_sizes, int n_in,
                              void* d_out, int out_size, void* d_ws, size_t ws_size,
                              hipStream_t stream) {
    const float* x  = (const float*)d_in[0];
    const int* eidx = (const int*)d_in[1];
    const float* W1 = (const float*)d_in[2];
    const float* b1 = (const float*)d_in[3];
    const float* W2 = (const float*)d_in[4];
    const float* b2 = (const float*)d_in[5];
    const float* Wc = (const float*)d_in[6];
    const float* bc = (const float*)d_in[7];
    float* out = (float*)d_out;

    const int N = in_sizes[0] / NFEAT;   // 50000 (< 65536 -> 16-bit node ids)
    const int E = in_sizes[1] / 2;       // 800000
    const int S = E + N;                 // total slots (no padding)
    const int* src = eidx;
    const int* dst = eidx + E;

    char* p = (char*)d_ws;
    auto alloc = [&](size_t bytes) { char* r = p; p += (bytes + 255) & ~(size_t)255; return r; };
    int*    deg    = (int*)   alloc((size_t)N * 4);
    float*  dinv   = (float*) alloc((size_t)N * 4);
    int*    eoffs  = (int*)   alloc((size_t)(N + 1) * 4);
    int*    ticket = (int*)   alloc((size_t)E * 4);
    uint*   colp32 = (uint*)  alloc(((size_t)S + 16) * 4);
    int*    rankgs = (int*)   alloc((size_t)(NSTREAMS + 1) * 4);
    int*    bsum   = (int*)   alloc((size_t)256 * 4);
    ushort* W1T    = (ushort*)alloc((size_t)128 * NFEAT * 2);
    ushort* W2T    = (ushort*)alloc((size_t)128 * NHID * 2);
    ushort* hs     = (ushort*)alloc((size_t)N * NHID * 2);   // 4 slices x N x 32
    ushort* g1     = (ushort*)alloc((size_t)N * NHID * 2);   // agg1 out, row-major bf16
    ushort* g2     = (ushort*)alloc((size_t)N * NHID * 2);   // agg2 out, row-major bf16

    const int nb = (N + SCAN_BS - 1) / SCAN_BS;

    k_init_tcast<<<((NFEAT + NHID) * 128 + 255) / 256, 256, 0, stream>>>(W1, W2, W1T, W2T, deg, N);
    k_count<<<(E + 255) / 256, 256, 0, stream>>>(dst, E, deg, ticket);
    k_scan1<<<nb, SCAN_BS, 0, stream>>>(deg, dinv, eoffs, bsum, N);
    k_scan3<<<nb, SCAN_BS, 0, stream>>>(eoffs, bsum, nb, N);
    k_fill_edges<<<(E + 255) / 256, 256, 0, stream>>>(src, dst, E, eoffs, ticket, colp32,
                                                      rankgs, N, S);

    const int gblocks = (N + 63) / 64;
    // layer 1
    k_gemm<1><<<gblocks, 256, 0, stream>>>(x, W1T, dinv, hs, N, NFEAT);
    k_aggs<<<AGG_BLOCKS, 256, 0, stream>>>(hs, colp32, rankgs, dinv, b1, g1, N);
    // layer 2
    k_gemm<0><<<gblocks, 256, 0, stream>>>(g1, W2T, dinv, hs, N, NHID);
    k_aggs<<<AGG_BLOCKS, 256, 0, stream>>>(hs, colp32, rankgs, dinv, b2, g2, N);
    // classifier
    k_classify<<<(N + 3) / 4, 256, 0, stream>>>(g2, Wc, bc, out, N);
}